// Round 5
// baseline (1871.925 us; speedup 1.0000x reference)
//
#include <hip/hip_runtime.h>
#include <hip/hip_bf16.h>

#define B_ 16
#define L_ 1024
#define D_ 512
#define K_ 64
#define NL_ 16
#define SMALL_ 8
#define SET_ 128

__device__ inline float waveSum(float v){
#pragma unroll
  for (int o=32;o>0;o>>=1) v += __shfl_down(v,o);
  return v;
}
__device__ inline float waveMax(float v){
#pragma unroll
  for (int o=32;o>0;o>>=1) v = fmaxf(v,__shfl_down(v,o));
  return v;
}

// ---- one-time: Wat[l][d][h] = W_att[l][h][d] for all layers ----
__global__ __launch_bounds__(256) void k_wt(const float* __restrict__ W, float* __restrict__ Wt){
  int l = blockIdx.x; int t = threadIdx.x;
  __shared__ float T[64][69];
  const float* src = W + (size_t)l*32768;
  float* dst = Wt + (size_t)l*32768;
  for (int dt=0; dt<8; ++dt){
#pragma unroll
    for (int i=0;i<4;i++){
      int idx=i*256+t; int h=idx>>4, dq=idx&15;
      float4 v = *reinterpret_cast<const float4*>(src + (size_t)h*512 + dt*64 + dq*4);
      T[dq*4+0][h]=v.x; T[dq*4+1][h]=v.y; T[dq*4+2][h]=v.z; T[dq*4+3][h]=v.w;
    }
    __syncthreads();
#pragma unroll
    for (int i=0;i<4;i++){
      int idx=i*256+t; int d=idx>>4, hq=idx&15;
      float4 o;
      o.x=T[d][hq*4+0]; o.y=T[d][hq*4+1]; o.z=T[d][hq*4+2]; o.w=T[d][hq*4+3];
      *reinterpret_cast<float4*>(dst + (size_t)(dt*64+d)*64 + hq*4) = o;
    }
    __syncthreads();
  }
}

// ---- rate GEMM: att2[b][l][h] = relu( temb[row,:] . Wat[:,h] + ba[h] )
// block: 32 rows x 64 heads; thread 2x4; TK=64; no in-kernel transposes.
__global__ __launch_bounds__(256) void k_rate_gemm(const float* __restrict__ temb,
    const float* __restrict__ Wat, const float* __restrict__ ba, float* __restrict__ att2){
  int r0 = blockIdx.x*32;            // global row (b*1024 + l)
  __shared__ float As[32][68];       // [row][k]
  __shared__ float Bs[64][68];       // [k][h]
  int t = threadIdx.x;
  int tc = t & 15, tr = t >> 4;      // tc -> 4 heads, tr -> 2 rows
  float acc[2][4] = {{0.f,0.f,0.f,0.f},{0.f,0.f,0.f,0.f}};
  for (int kc=0; kc<512; kc+=64){
#pragma unroll
    for (int i=0;i<2;i++){           // stage A row-major, conflict-free
      int idx = i*256 + t;
      int row = idx>>4, kq = idx&15;
      *reinterpret_cast<float4*>(&As[row][kq*4]) =
        *reinterpret_cast<const float4*>(temb + (size_t)(r0+row)*512 + kc + kq*4);
    }
#pragma unroll
    for (int i=0;i<4;i++){           // stage B from pre-transposed Wat, conflict-free
      int idx = i*256 + t;
      int k = idx>>4, hq = idx&15;
      *reinterpret_cast<float4*>(&Bs[k][hq*4]) =
        *reinterpret_cast<const float4*>(Wat + (size_t)(kc+k)*64 + hq*4);
    }
    __syncthreads();
#pragma unroll 8
    for (int k=0;k<64;++k){
      float a0 = As[tr*2+0][k];      // broadcast across 16 lanes
      float a1 = As[tr*2+1][k];
      float4 b = *reinterpret_cast<const float4*>(&Bs[k][tc*4]);
      acc[0][0]+=a0*b.x; acc[0][1]+=a0*b.y; acc[0][2]+=a0*b.z; acc[0][3]+=a0*b.w;
      acc[1][0]+=a1*b.x; acc[1][1]+=a1*b.y; acc[1][2]+=a1*b.z; acc[1][3]+=a1*b.w;
    }
    __syncthreads();
  }
  float4 bb = *reinterpret_cast<const float4*>(ba + tc*4);
#pragma unroll
  for (int j=0;j<2;j++){
    float4 o;
    o.x = fmaxf(acc[j][0]+bb.x, 0.f);
    o.y = fmaxf(acc[j][1]+bb.y, 0.f);
    o.z = fmaxf(acc[j][2]+bb.z, 0.f);
    o.w = fmaxf(acc[j][3]+bb.w, 0.f);
    *reinterpret_cast<float4*>(att2 + (size_t)(r0 + tr*2 + j)*64 + tc*4) = o;  // coalesced
  }
}

// ---- softmax over sequence dim per (b,k), in place on att2[B,L,K] ----
__global__ __launch_bounds__(256) void k_softmax(float* __restrict__ att2){
  int b = blockIdx.x >> 6, k = blockIdx.x & 63;
  float* base = att2 + (size_t)b*L_*K_ + k;
  int tid = threadIdx.x;
  float v[4];
  float mx = -1e30f;
#pragma unroll
  for (int i=0;i<4;i++){ v[i] = base[(size_t)(tid + i*256)*64]; mx = fmaxf(mx, v[i]); }
  __shared__ float red[8];
  int wave = tid>>6, lane = tid&63;
  float wm = waveMax(mx);
  if (lane==0) red[wave] = wm;
  __syncthreads();
  mx = fmaxf(fmaxf(red[0],red[1]),fmaxf(red[2],red[3]));
  float sum = 0.f;
#pragma unroll
  for (int i=0;i<4;i++){ v[i] = __expf(v[i]-mx); sum += v[i]; }
  float ws = waveSum(sum);
  if (lane==0) red[4+wave] = ws;
  __syncthreads();
  sum = red[4]+red[5]+red[6]+red[7];
  float inv = 1.0f/sum;
#pragma unroll
  for (int i=0;i<4;i++) base[(size_t)(tid + i*256)*64] = v[i]*inv;
}

// ---- spart GEMM: spart[b][lc][k][d] = sum_{l in chunk} att2[b,l,k]*temb[b,l,d]
// block: (dt,lc,b); C[64k x 64d]; thread 4x4; no transposes.
__global__ __launch_bounds__(256) void k_spart_gemm(const float* __restrict__ temb,
    const float* __restrict__ att2, float* __restrict__ spart){
  int dt = blockIdx.x;   // 0..7
  int lc = blockIdx.y;   // 0..3
  int b  = blockIdx.z;
  __shared__ float As[32][68];   // [l][k]  from att2 (natural layout)
  __shared__ float Bs[32][68];   // [l][d]  from temb
  int t = threadIdx.x;
  int tc = t & 15, tr = t >> 4;  // tc -> 4 d, tr -> 4 k
  float acc[4][4] = {{0,0,0,0},{0,0,0,0},{0,0,0,0},{0,0,0,0}};
  int lbase = lc*256;
  for (int ls=0; ls<256; ls+=32){
#pragma unroll
    for (int i=0;i<2;i++){
      int idx = i*256 + t;
      int l = idx>>4, kq = idx&15;
      *reinterpret_cast<float4*>(&As[l][kq*4]) =
        *reinterpret_cast<const float4*>(att2 + ((size_t)(b*L_ + lbase + ls + l))*64 + kq*4);
    }
#pragma unroll
    for (int i=0;i<2;i++){
      int idx = i*256 + t;
      int l = idx>>4, dq = idx&15;
      *reinterpret_cast<float4*>(&Bs[l][dq*4]) =
        *reinterpret_cast<const float4*>(temb + ((size_t)(b*L_) + lbase + ls + l)*512 + dt*64 + dq*4);
    }
    __syncthreads();
#pragma unroll 8
    for (int l=0;l<32;++l){
      float4 a = *reinterpret_cast<const float4*>(&As[l][tr*4]);
      float4 bb = *reinterpret_cast<const float4*>(&Bs[l][tc*4]);
      acc[0][0]+=a.x*bb.x; acc[0][1]+=a.x*bb.y; acc[0][2]+=a.x*bb.z; acc[0][3]+=a.x*bb.w;
      acc[1][0]+=a.y*bb.x; acc[1][1]+=a.y*bb.y; acc[1][2]+=a.y*bb.z; acc[1][3]+=a.y*bb.w;
      acc[2][0]+=a.z*bb.x; acc[2][1]+=a.z*bb.y; acc[2][2]+=a.z*bb.z; acc[2][3]+=a.z*bb.w;
      acc[3][0]+=a.w*bb.x; acc[3][1]+=a.w*bb.y; acc[3][2]+=a.w*bb.z; acc[3][3]+=a.w*bb.w;
    }
    __syncthreads();
  }
#pragma unroll
  for (int i=0;i<4;i++){
    float4 o; o.x=acc[i][0]; o.y=acc[i][1]; o.z=acc[i][2]; o.w=acc[i][3];
    *reinterpret_cast<float4*>(&spart[((size_t)((b*4+lc)*64 + tr*4+i))*512 + dt*64 + tc*4]) = o;
  }
}

// ---- reduce partials, scale, LN(ga,bea), vec = relu(s@Wp+bp) -> fiin[b][e*64+k] ----
__global__ __launch_bounds__(64) void k_sln_vec(const float* __restrict__ spart,
     const float* __restrict__ ga, const float* __restrict__ bea,
     const float* __restrict__ Wp, const float* __restrict__ bp,
     float* __restrict__ fiin){
  int bk = blockIdx.x; int b = bk>>6, k = bk&63;
  int lane = threadIdx.x;
  int d0 = lane*8;
  float sv[8];
#pragma unroll
  for (int j=0;j<8;j++) sv[j]=0.f;
#pragma unroll
  for (int lc=0;lc<4;lc++){
    const float* p = spart + ((size_t)((b*4+lc)*64 + k))*512 + d0;
    float4 x0 = *reinterpret_cast<const float4*>(p);
    float4 x1 = *reinterpret_cast<const float4*>(p+4);
    sv[0]+=x0.x; sv[1]+=x0.y; sv[2]+=x0.z; sv[3]+=x0.w;
    sv[4]+=x1.x; sv[5]+=x1.y; sv[6]+=x1.z; sv[7]+=x1.w;
  }
  const float inv_sqrt_L = 0.03125f;
  float s1=0.f, s2=0.f;
#pragma unroll
  for (int j=0;j<8;j++){ sv[j]*=inv_sqrt_L; s1+=sv[j]; s2+=sv[j]*sv[j]; }
#pragma unroll
  for (int o=32;o>0;o>>=1){ s1 += __shfl_xor(s1,o); s2 += __shfl_xor(s2,o); }
  float m = s1*(1.0f/512.0f);
  float var = s2*(1.0f/512.0f) - m*m;
  float rstd = rsqrtf(var + 1e-5f);
  const float* gap = ga + (size_t)k*512 + d0;
  const float* bep = bea + (size_t)k*512 + d0;
  float4 g0 = *reinterpret_cast<const float4*>(gap);
  float4 g1 = *reinterpret_cast<const float4*>(gap+4);
  float4 e0 = *reinterpret_cast<const float4*>(bep);
  float4 e1 = *reinterpret_cast<const float4*>(bep+4);
  float gav[8] = {g0.x,g0.y,g0.z,g0.w,g1.x,g1.y,g1.z,g1.w};
  float bev[8] = {e0.x,e0.y,e0.z,e0.w,e1.x,e1.y,e1.z,e1.w};
  float acc[8];
#pragma unroll
  for (int e=0;e<8;e++) acc[e]=0.f;
#pragma unroll
  for (int j=0;j<8;j++){
    float sl = (sv[j]-m)*rstd*gav[j] + bev[j];
    const float* wp = Wp + ((size_t)k*512 + d0 + j)*8;
    float4 w0 = *reinterpret_cast<const float4*>(wp);
    float4 w1 = *reinterpret_cast<const float4*>(wp+4);
    acc[0]+=sl*w0.x; acc[1]+=sl*w0.y; acc[2]+=sl*w0.z; acc[3]+=sl*w0.w;
    acc[4]+=sl*w1.x; acc[5]+=sl*w1.y; acc[6]+=sl*w1.z; acc[7]+=sl*w1.w;
  }
#pragma unroll
  for (int e=0;e<8;e++) acc[e] = waveSum(acc[e]);
  if (lane==0){
#pragma unroll
    for (int e=0;e<8;e++)
      fiin[(size_t)b*512 + e*64 + k] = fmaxf(acc[e] + bp[k*8+e], 0.f);
  }
}

// ---- FI linear (+relu+residual): res[b][o] over grid (oc=8, b=16) ----
__global__ __launch_bounds__(256) void k_fi(const float* __restrict__ fiin,
    const float* __restrict__ Wf, const float* __restrict__ bfi, float* __restrict__ res){
  int oc = blockIdx.x, b = blockIdx.y;
  int tid = threadIdx.x;
  int og = tid & 63, q = tid >> 6;
  int o = oc*64 + og;
  __shared__ float row[512];
  __shared__ float part[4][64];
  reinterpret_cast<float2*>(row)[tid] = reinterpret_cast<const float2*>(fiin + (size_t)b*512)[tid];
  __syncthreads();
  float acc = 0.f;
  const float* wp = Wf + (size_t)(q*128)*512 + o;
  const float* rp = &row[q*128];
#pragma unroll 4
  for (int d=0; d<128; ++d) acc += rp[d] * wp[(size_t)d*512];
  part[q][og] = acc;
  __syncthreads();
  if (q==0){
    float s = part[0][og]+part[1][og]+part[2][og]+part[3][og];
    res[(size_t)b*512 + o] = fmaxf(s + bfi[o], 0.f) + row[o];
  }
}

// ---- Set linear (+relu): vec[b][o2] over grid (oc=2, b=16) ----
__global__ __launch_bounds__(256) void k_set(const float* __restrict__ res,
    const float* __restrict__ Ws, const float* __restrict__ bs, float* __restrict__ vecst_l){
  int oc = blockIdx.x, b = blockIdx.y;
  int tid = threadIdx.x;
  int og = tid & 63, q = tid >> 6;
  int o = oc*64 + og;
  __shared__ float row[512];
  __shared__ float part[4][64];
  reinterpret_cast<float2*>(row)[tid] = reinterpret_cast<const float2*>(res + (size_t)b*512)[tid];
  __syncthreads();
  float acc = 0.f;
  const float* wp = Ws + (size_t)(q*128)*128 + o;
  const float* rp = &row[q*128];
#pragma unroll 4
  for (int d=0; d<128; ++d) acc += rp[d] * wp[(size_t)d*128];
  part[q][og] = acc;
  __syncthreads();
  if (q==0){
    vecst_l[(size_t)b*128 + o] = fmaxf(part[0][og]+part[1][og]+part[2][og]+part[3][og] + bs[o], 0.f);
  }
}

// ---- sum_att (contiguous from att2), att_dis output, t_emb update with LN ----
__global__ __launch_bounds__(256) void k_update(float* __restrict__ temb, const float* __restrict__ att2,
    const float* __restrict__ wp1, const float* __restrict__ bp1,
    const float* __restrict__ gn, const float* __restrict__ ben,
    float* __restrict__ attdis, int layer){
  int bl = blockIdx.x;            // 0..B*L-1
  int tid = threadIdx.x;
  __shared__ float sred[9];
  int wave = tid>>6, lane = tid&63;
  if (tid < 64){
    float a = att2[(size_t)bl*64 + tid];   // contiguous 256B
    float t = waveSum(a);
    if (tid==0){
      sred[8] = t;
      int b = bl >> 10, lseq = bl & 1023;
      attdis[(size_t)(layer*B_ + b)*L_ + lseq] = t;
    }
  }
  __syncthreads();
  float sa = sred[8];
  int d0 = tid*2;
  float2 e = *reinterpret_cast<const float2*>(&temb[(size_t)bl*512 + d0]);
  float2 uw  = *reinterpret_cast<const float2*>(wp1 + d0);
  float2 ubp = *reinterpret_cast<const float2*>(bp1 + d0);
  float v0 = e.x * (sa*uw.x + ubp.x + 1.0f);
  float v1 = e.y * (sa*uw.y + ubp.y + 1.0f);
  float s1 = v0+v1, s2 = v0*v0+v1*v1;
  float w1 = waveSum(s1), w2 = waveSum(s2);
  if (lane==0){ sred[wave]=w1; sred[4+wave]=w2; }
  __syncthreads();
  s1 = sred[0]+sred[1]+sred[2]+sred[3];
  s2 = sred[4]+sred[5]+sred[6]+sred[7];
  float m = s1*(1.f/512.f);
  float var = s2*(1.f/512.f) - m*m;
  float rstd = rsqrtf(var+1e-5f);
  float2 ug  = *reinterpret_cast<const float2*>(gn + d0);
  float2 ube = *reinterpret_cast<const float2*>(ben + d0);
  float2 o;
  o.x = (v0-m)*rstd*ug.x + ube.x;
  o.y = (v1-m)*rstd*ug.y + ube.y;
  *reinterpret_cast<float2*>(&temb[(size_t)bl*512 + d0]) = o;
}

// ---- final attention rate ----
__global__ __launch_bounds__(64) void k_aat_rate(const float* __restrict__ temb,
    const float* __restrict__ w_aat, const float* __restrict__ b_aat, float* __restrict__ ratef){
  int bl = blockIdx.x; int lane = threadIdx.x;
  const float* rp = temb + (size_t)bl*512 + lane*8;
  float4 e0 = *reinterpret_cast<const float4*>(rp);
  float4 e1 = *reinterpret_cast<const float4*>(rp+4);
  const float* wp = w_aat + lane*8;
  float4 w0 = *reinterpret_cast<const float4*>(wp);
  float4 w1 = *reinterpret_cast<const float4*>(wp+4);
  float s = e0.x*w0.x+e0.y*w0.y+e0.z*w0.z+e0.w*w0.w
          + e1.x*w1.x+e1.y*w1.y+e1.z*w1.z+e1.w*w1.w;
  s = waveSum(s);
  if (lane==0) ratef[bl] = fmaxf(s + b_aat[0], 0.f);
}

// ---- softmax over a contiguous 1024-run per block ----
__global__ __launch_bounds__(256) void k_softmax_seq(float* __restrict__ ratef){
  int b = blockIdx.x; int tid = threadIdx.x;
  float* base = ratef + (size_t)b*1024;
  float4 v = reinterpret_cast<float4*>(base)[tid];
  float mx = fmaxf(fmaxf(v.x,v.y),fmaxf(v.z,v.w));
  __shared__ float red[8];
  int wave=tid>>6, lane=tid&63;
  float wm = waveMax(mx);
  if(lane==0) red[wave]=wm;
  __syncthreads();
  mx = fmaxf(fmaxf(red[0],red[1]),fmaxf(red[2],red[3]));
  v.x=__expf(v.x-mx); v.y=__expf(v.y-mx); v.z=__expf(v.z-mx); v.w=__expf(v.w-mx);
  float s = v.x+v.y+v.z+v.w;
  float wsum = waveSum(s);
  if(lane==0) red[4+wave]=wsum;
  __syncthreads();
  s = red[4]+red[5]+red[6]+red[7];
  float inv = 1.f/s;
  v.x*=inv;v.y*=inv;v.z*=inv;v.w*=inv;
  reinterpret_cast<float4*>(base)[tid] = v;
}

// ---- final pool partials ----
__global__ __launch_bounds__(256) void k_poolA(const float* __restrict__ temb, const float* __restrict__ attf,
                                               float* __restrict__ sraw){
  int dc = blockIdx.x, b = blockIdx.y;
  int tid = threadIdx.x;
  int dl = tid & 63, q = tid >> 6;
  int d = dc*64 + dl;
  __shared__ float sA[1024];
  __shared__ float part[4][64];
  reinterpret_cast<float4*>(sA)[tid] = reinterpret_cast<const float4*>(attf + (size_t)b*1024)[tid];
  __syncthreads();
  float acc = 0.f;
  const float* tp = temb + ((size_t)b*1024 + q*256)*512 + d;
  const float* ap = &sA[q*256];
#pragma unroll 4
  for (int l=0;l<256;++l) acc += tp[(size_t)l*512]*ap[l];
  part[q][dl] = acc;
  __syncthreads();
  if (q==0) sraw[(size_t)b*512 + d] = (part[0][dl]+part[1][dl]+part[2][dl]+part[3][dl])*0.03125f;
}

// ---- final pool LN ----
__global__ __launch_bounds__(256) void k_poolB(const float* __restrict__ sraw,
   const float* __restrict__ g_aat, const float* __restrict__ be_aat, float* __restrict__ spool){
  int b = blockIdx.x; int tid = threadIdx.x;
  int d0 = tid*2;
  float2 a = *reinterpret_cast<const float2*>(&sraw[(size_t)b*512 + d0]);
  __shared__ float red[8];
  int wave=tid>>6,lane=tid&63;
  float s1 = a.x+a.y, s2 = a.x*a.x+a.y*a.y;
  float w1=waveSum(s1), w2=waveSum(s2);
  if(lane==0){red[wave]=w1; red[4+wave]=w2;}
  __syncthreads();
  s1=red[0]+red[1]+red[2]+red[3];
  s2=red[4]+red[5]+red[6]+red[7];
  float m=s1*(1.f/512.f), var=s2*(1.f/512.f)-m*m, rstd=rsqrtf(var+1e-5f);
  float2 ug=*reinterpret_cast<const float2*>(g_aat+d0);
  float2 ub=*reinterpret_cast<const float2*>(be_aat+d0);
  spool[(size_t)b*512+d0]   = (a.x-m)*rstd*ug.x+ub.x;
  spool[(size_t)b*512+d0+1] = (a.y-m)*rstd*ug.y+ub.y;
}

// ---- final head ----
__global__ __launch_bounds__(256) void k_final(const float* __restrict__ spool, const float* __restrict__ vecst,
    const float* __restrict__ Wh, const float* __restrict__ bh, float* __restrict__ Pout){
  int b = blockIdx.x; int tid = threadIdx.x;
  float part = 0.f;
  for (int i = tid; i < 2560; i += 256){
    float v;
    if (i < 512) v = spool[(size_t)b*512 + i];
    else {
      int j = i - 512;
      v = vecst[(size_t)(j>>7)*(B_*SET_) + b*SET_ + (j&127)];
    }
    part += v * Wh[i];
  }
  __shared__ float red[4];
  int wave=tid>>6,lane=tid&63;
  float w = waveSum(part);
  if(lane==0) red[wave]=w;
  __syncthreads();
  if (tid==0){
    float x = red[0]+red[1]+red[2]+red[3] + bh[0];
    Pout[b] = 1.0f/(1.0f+expf(-x));
  }
}

extern "C" void kernel_launch(void* const* d_in, const int* in_sizes, int n_in,
                              void* d_out, int out_size, void* d_ws, size_t ws_size,
                              hipStream_t stream){
  const float* emb   = (const float*)d_in[0];
  const float* W_att = (const float*)d_in[1];
  const float* b_att = (const float*)d_in[2];
  const float* g_att = (const float*)d_in[3];
  const float* be_att= (const float*)d_in[4];
  const float* W_pro = (const float*)d_in[5];
  const float* b_pro = (const float*)d_in[6];
  const float* w_p1  = (const float*)d_in[7];
  const float* b_p1  = (const float*)d_in[8];
  const float* W_FI  = (const float*)d_in[9];
  const float* b_FI  = (const float*)d_in[10];
  const float* W_Set = (const float*)d_in[11];
  const float* b_Set = (const float*)d_in[12];
  const float* g_n   = (const float*)d_in[13];
  const float* be_n  = (const float*)d_in[14];
  const float* w_aat = (const float*)d_in[15];
  const float* b_aat = (const float*)d_in[16];
  const float* g_aat = (const float*)d_in[17];
  const float* be_aat= (const float*)d_in[18];
  const float* W_h2p = (const float*)d_in[19];
  const float* b_h2p = (const float*)d_in[20];
  float* out = (float*)d_out;

  float* ws = (float*)d_ws;
  float* temb  = ws;                      // 8,388,608
  float* att2  = temb + 8388608;          // 1,048,576  [B][L][K]
  float* spart = att2 + 1048576;          // 2,097,152
  float* fiin  = spart + 2097152;         // 8,192
  float* vecst = fiin + 8192;             // 131,072
  float* ratef = vecst + 131072;          // 16,384
  float* spool = ratef + 16384;           // 8,192
  float* res   = spool + 8192;            // 8,192
  float* sraw  = res + 8192;              // 8,192
  float* Wat   = sraw + 8192;             // 524,288  [NL][D][K]

  hipMemcpyAsync(temb, emb, (size_t)8388608*4, hipMemcpyDeviceToDevice, stream);
  k_wt<<<16,256,0,stream>>>(W_att, Wat);
  for (int l=0; l<16; ++l){
    k_rate_gemm<<<512,256,0,stream>>>(temb, Wat + (size_t)l*32768, b_att + l*64, att2);
    k_softmax<<<1024,256,0,stream>>>(att2);
    k_spart_gemm<<<dim3(8,4,16),256,0,stream>>>(temb, att2, spart);
    k_sln_vec<<<1024,64,0,stream>>>(spart, g_att + (size_t)l*32768, be_att + (size_t)l*32768,
                                    W_pro + (size_t)l*262144, b_pro + l*512, fiin);
    k_fi<<<dim3(8,16),256,0,stream>>>(fiin, W_FI + (size_t)l*262144, b_FI + l*512, res);
    k_set<<<dim3(2,16),256,0,stream>>>(res, W_Set + (size_t)l*65536, b_Set + l*128,
                                       vecst + (size_t)l*2048);
    k_update<<<16384,256,0,stream>>>(temb, att2, w_p1 + l*512, b_p1 + l*512,
                                     g_n + l*512, be_n + l*512, out + 16, l);
  }
  k_aat_rate<<<16384,64,0,stream>>>(temb, w_aat, b_aat, ratef);
  k_softmax_seq<<<16,256,0,stream>>>(ratef);
  k_poolA<<<dim3(8,16),256,0,stream>>>(temb, ratef, sraw);
  k_poolB<<<16,256,0,stream>>>(sraw, g_aat, be_aat, spool);
  k_final<<<16,256,0,stream>>>(spool, vecst, W_h2p, b_h2p, out);
}

// Round 6
// 1747.696 us; speedup vs baseline: 1.0711x; 1.0711x over previous
//
#include <hip/hip_runtime.h>
#include <hip/hip_bf16.h>

#define B_ 16
#define L_ 1024
#define D_ 512
#define K_ 64
#define NL_ 16
#define SMALL_ 8
#define SET_ 128

__device__ inline float waveSum(float v){
#pragma unroll
  for (int o=32;o>0;o>>=1) v += __shfl_down(v,o);
  return v;
}
__device__ inline float waveMax(float v){
#pragma unroll
  for (int o=32;o>0;o>>=1) v = fmaxf(v,__shfl_down(v,o));
  return v;
}

// ---- one-time: Wat[l][d][h] = W_att[l][h][d] for all layers ----
__global__ __launch_bounds__(256) void k_wt(const float* __restrict__ W, float* __restrict__ Wt){
  int l = blockIdx.x; int t = threadIdx.x;
  __shared__ float T[64][69];
  const float* src = W + (size_t)l*32768;
  float* dst = Wt + (size_t)l*32768;
  for (int dt=0; dt<8; ++dt){
#pragma unroll
    for (int i=0;i<4;i++){
      int idx=i*256+t; int h=idx>>4, dq=idx&15;
      float4 v = *reinterpret_cast<const float4*>(src + (size_t)h*512 + dt*64 + dq*4);
      T[dq*4+0][h]=v.x; T[dq*4+1][h]=v.y; T[dq*4+2][h]=v.z; T[dq*4+3][h]=v.w;
    }
    __syncthreads();
#pragma unroll
    for (int i=0;i<4;i++){
      int idx=i*256+t; int d=idx>>4, hq=idx&15;
      float4 o;
      o.x=T[d][hq*4+0]; o.y=T[d][hq*4+1]; o.z=T[d][hq*4+2]; o.w=T[d][hq*4+3];
      *reinterpret_cast<float4*>(dst + (size_t)(dt*64+d)*64 + hq*4) = o;
    }
    __syncthreads();
  }
}

// ---- rate GEMM: att2[b][l][h] = relu( temb[row,:] . Wat[:,h] + ba[h] ) ----
__global__ __launch_bounds__(256) void k_rate_gemm(const float* __restrict__ temb,
    const float* __restrict__ Wat, const float* __restrict__ ba, float* __restrict__ att2){
  int r0 = blockIdx.x*32;            // global row (b*1024 + l)
  __shared__ float As[32][68];       // [row][k]
  __shared__ float Bs[64][68];       // [k][h]
  int t = threadIdx.x;
  int tc = t & 15, tr = t >> 4;      // tc -> 4 heads, tr -> 2 rows
  float acc[2][4] = {{0.f,0.f,0.f,0.f},{0.f,0.f,0.f,0.f}};
  for (int kc=0; kc<512; kc+=64){
#pragma unroll
    for (int i=0;i<2;i++){
      int idx = i*256 + t;
      int row = idx>>4, kq = idx&15;
      *reinterpret_cast<float4*>(&As[row][kq*4]) =
        *reinterpret_cast<const float4*>(temb + (size_t)(r0+row)*512 + kc + kq*4);
    }
#pragma unroll
    for (int i=0;i<4;i++){
      int idx = i*256 + t;
      int k = idx>>4, hq = idx&15;
      *reinterpret_cast<float4*>(&Bs[k][hq*4]) =
        *reinterpret_cast<const float4*>(Wat + (size_t)(kc+k)*64 + hq*4);
    }
    __syncthreads();
#pragma unroll 8
    for (int k=0;k<64;++k){
      float a0 = As[tr*2+0][k];
      float a1 = As[tr*2+1][k];
      float4 b = *reinterpret_cast<const float4*>(&Bs[k][tc*4]);
      acc[0][0]+=a0*b.x; acc[0][1]+=a0*b.y; acc[0][2]+=a0*b.z; acc[0][3]+=a0*b.w;
      acc[1][0]+=a1*b.x; acc[1][1]+=a1*b.y; acc[1][2]+=a1*b.z; acc[1][3]+=a1*b.w;
    }
    __syncthreads();
  }
  float4 bb = *reinterpret_cast<const float4*>(ba + tc*4);
#pragma unroll
  for (int j=0;j<2;j++){
    float4 o;
    o.x = fmaxf(acc[j][0]+bb.x, 0.f);
    o.y = fmaxf(acc[j][1]+bb.y, 0.f);
    o.z = fmaxf(acc[j][2]+bb.z, 0.f);
    o.w = fmaxf(acc[j][3]+bb.w, 0.f);
    *reinterpret_cast<float4*>(att2 + (size_t)(r0 + tr*2 + j)*64 + tc*4) = o;
  }
}

// ---- per-(b,k) chunk stats over 256 l's: max and exp-sum (coalesced) ----
__global__ __launch_bounds__(256) void k_stat64(const float* __restrict__ att2,
    float* __restrict__ maxs4, float* __restrict__ sums4){
  int lc = blockIdx.x, b = blockIdx.y;
  int t = threadIdx.x;
  int r = t>>4, c = t&15;
  const float* base = att2 + ((size_t)(b*L_ + lc*256))*64 + c*4;
  float4 m4 = make_float4(-1e30f,-1e30f,-1e30f,-1e30f);
  for (int it=0; it<16; ++it){
    float4 v = *reinterpret_cast<const float4*>(base + (size_t)(it*16 + r)*64);
    m4.x=fmaxf(m4.x,v.x); m4.y=fmaxf(m4.y,v.y); m4.z=fmaxf(m4.z,v.z); m4.w=fmaxf(m4.w,v.w);
  }
  __shared__ float red[16][16][4];
  __shared__ float cmax[64];
  *reinterpret_cast<float4*>(&red[r][c][0]) = m4;
  __syncthreads();
  if (t < 64){
    int cc=t>>2, j=t&3;
    float m = red[0][cc][j];
#pragma unroll
    for (int rr=1;rr<16;rr++) m = fmaxf(m, red[rr][cc][j]);
    cmax[t] = m;
  }
  __syncthreads();
  float4 mx = *reinterpret_cast<const float4*>(&cmax[c*4]);
  float4 s4 = make_float4(0.f,0.f,0.f,0.f);
  for (int it=0; it<16; ++it){
    float4 v = *reinterpret_cast<const float4*>(base + (size_t)(it*16 + r)*64);
    s4.x += __expf(v.x-mx.x); s4.y += __expf(v.y-mx.y);
    s4.z += __expf(v.z-mx.z); s4.w += __expf(v.w-mx.w);
  }
  __syncthreads();
  *reinterpret_cast<float4*>(&red[r][c][0]) = s4;
  __syncthreads();
  if (t < 64){
    int cc=t>>2, j=t&3;
    float s = 0.f;
#pragma unroll
    for (int rr=0;rr<16;rr++) s += red[rr][cc][j];
    maxs4[((size_t)(b*4+lc))*64 + t] = cmax[t];
    sums4[((size_t)(b*4+lc))*64 + t] = s;
  }
}

// ---- combine chunk stats -> smax[b][k], sinv[b][k] ----
__global__ __launch_bounds__(64) void k_statc(const float* __restrict__ maxs4,
    const float* __restrict__ sums4, float* __restrict__ smax, float* __restrict__ sinv){
  int b = blockIdx.x; int k = threadIdx.x;
  float m0 = maxs4[((size_t)(b*4+0))*64+k], m1 = maxs4[((size_t)(b*4+1))*64+k];
  float m2 = maxs4[((size_t)(b*4+2))*64+k], m3 = maxs4[((size_t)(b*4+3))*64+k];
  float g = fmaxf(fmaxf(m0,m1),fmaxf(m2,m3));
  float s = sums4[((size_t)(b*4+0))*64+k]*__expf(m0-g)
          + sums4[((size_t)(b*4+1))*64+k]*__expf(m1-g)
          + sums4[((size_t)(b*4+2))*64+k]*__expf(m2-g)
          + sums4[((size_t)(b*4+3))*64+k]*__expf(m3-g);
  smax[b*64+k] = g;
  sinv[b*64+k] = 1.0f/s;
}

// ---- spart GEMM with inline softmax-normalize on A-staging ----
__global__ __launch_bounds__(256) void k_spart_gemm(const float* __restrict__ temb,
    const float* __restrict__ att2, const float* __restrict__ smax, const float* __restrict__ sinv,
    float* __restrict__ spart){
  int dt = blockIdx.x;   // 0..7
  int lc = blockIdx.y;   // 0..3
  int b  = blockIdx.z;
  __shared__ float As[32][68];   // [l][k]  normalized att
  __shared__ float Bs[32][68];   // [l][d]  temb
  int t = threadIdx.x;
  int tc = t & 15, tr = t >> 4;
  int kq4 = (t&15)*4;
  float4 mx = *reinterpret_cast<const float4*>(smax + b*64 + kq4);
  float4 iv = *reinterpret_cast<const float4*>(sinv + b*64 + kq4);
  float acc[4][4] = {{0,0,0,0},{0,0,0,0},{0,0,0,0},{0,0,0,0}};
  int lbase = lc*256;
  for (int ls=0; ls<256; ls+=32){
#pragma unroll
    for (int i=0;i<2;i++){
      int idx = i*256 + t;
      int l = idx>>4;
      float4 v = *reinterpret_cast<const float4*>(att2 + ((size_t)(b*L_ + lbase + ls + l))*64 + kq4);
      v.x = __expf(v.x-mx.x)*iv.x; v.y = __expf(v.y-mx.y)*iv.y;
      v.z = __expf(v.z-mx.z)*iv.z; v.w = __expf(v.w-mx.w)*iv.w;
      *reinterpret_cast<float4*>(&As[l][kq4]) = v;
    }
#pragma unroll
    for (int i=0;i<2;i++){
      int idx = i*256 + t;
      int l = idx>>4, dq = idx&15;
      *reinterpret_cast<float4*>(&Bs[l][dq*4]) =
        *reinterpret_cast<const float4*>(temb + ((size_t)(b*L_) + lbase + ls + l)*512 + dt*64 + dq*4);
    }
    __syncthreads();
#pragma unroll 8
    for (int l=0;l<32;++l){
      float4 a = *reinterpret_cast<const float4*>(&As[l][tr*4]);
      float4 bb = *reinterpret_cast<const float4*>(&Bs[l][tc*4]);
      acc[0][0]+=a.x*bb.x; acc[0][1]+=a.x*bb.y; acc[0][2]+=a.x*bb.z; acc[0][3]+=a.x*bb.w;
      acc[1][0]+=a.y*bb.x; acc[1][1]+=a.y*bb.y; acc[1][2]+=a.y*bb.z; acc[1][3]+=a.y*bb.w;
      acc[2][0]+=a.z*bb.x; acc[2][1]+=a.z*bb.y; acc[2][2]+=a.z*bb.z; acc[2][3]+=a.z*bb.w;
      acc[3][0]+=a.w*bb.x; acc[3][1]+=a.w*bb.y; acc[3][2]+=a.w*bb.z; acc[3][3]+=a.w*bb.w;
    }
    __syncthreads();
  }
#pragma unroll
  for (int i=0;i<4;i++){
    float4 o; o.x=acc[i][0]; o.y=acc[i][1]; o.z=acc[i][2]; o.w=acc[i][3];
    *reinterpret_cast<float4*>(&spart[((size_t)((b*4+lc)*64 + tr*4+i))*512 + dt*64 + tc*4]) = o;
  }
}

// ---- reduce partials, scale, LN(ga,bea), vec = relu(s@Wp+bp) -> fiin[b][e*64+k] ----
__global__ __launch_bounds__(64) void k_sln_vec(const float* __restrict__ spart,
     const float* __restrict__ ga, const float* __restrict__ bea,
     const float* __restrict__ Wp, const float* __restrict__ bp,
     float* __restrict__ fiin){
  int bk = blockIdx.x; int b = bk>>6, k = bk&63;
  int lane = threadIdx.x;
  int d0 = lane*8;
  float sv[8];
#pragma unroll
  for (int j=0;j<8;j++) sv[j]=0.f;
#pragma unroll
  for (int lc=0;lc<4;lc++){
    const float* p = spart + ((size_t)((b*4+lc)*64 + k))*512 + d0;
    float4 x0 = *reinterpret_cast<const float4*>(p);
    float4 x1 = *reinterpret_cast<const float4*>(p+4);
    sv[0]+=x0.x; sv[1]+=x0.y; sv[2]+=x0.z; sv[3]+=x0.w;
    sv[4]+=x1.x; sv[5]+=x1.y; sv[6]+=x1.z; sv[7]+=x1.w;
  }
  const float inv_sqrt_L = 0.03125f;
  float s1=0.f, s2=0.f;
#pragma unroll
  for (int j=0;j<8;j++){ sv[j]*=inv_sqrt_L; s1+=sv[j]; s2+=sv[j]*sv[j]; }
#pragma unroll
  for (int o=32;o>0;o>>=1){ s1 += __shfl_xor(s1,o); s2 += __shfl_xor(s2,o); }
  float m = s1*(1.0f/512.0f);
  float var = s2*(1.0f/512.0f) - m*m;
  float rstd = rsqrtf(var + 1e-5f);
  const float* gap = ga + (size_t)k*512 + d0;
  const float* bep = bea + (size_t)k*512 + d0;
  float4 g0 = *reinterpret_cast<const float4*>(gap);
  float4 g1 = *reinterpret_cast<const float4*>(gap+4);
  float4 e0 = *reinterpret_cast<const float4*>(bep);
  float4 e1 = *reinterpret_cast<const float4*>(bep+4);
  float gav[8] = {g0.x,g0.y,g0.z,g0.w,g1.x,g1.y,g1.z,g1.w};
  float bev[8] = {e0.x,e0.y,e0.z,e0.w,e1.x,e1.y,e1.z,e1.w};
  float acc[8];
#pragma unroll
  for (int e=0;e<8;e++) acc[e]=0.f;
#pragma unroll
  for (int j=0;j<8;j++){
    float sl = (sv[j]-m)*rstd*gav[j] + bev[j];
    const float* wp = Wp + ((size_t)k*512 + d0 + j)*8;
    float4 w0 = *reinterpret_cast<const float4*>(wp);
    float4 w1 = *reinterpret_cast<const float4*>(wp+4);
    acc[0]+=sl*w0.x; acc[1]+=sl*w0.y; acc[2]+=sl*w0.z; acc[3]+=sl*w0.w;
    acc[4]+=sl*w1.x; acc[5]+=sl*w1.y; acc[6]+=sl*w1.z; acc[7]+=sl*w1.w;
  }
#pragma unroll
  for (int e=0;e<8;e++) acc[e] = waveSum(acc[e]);
  if (lane==0){
#pragma unroll
    for (int e=0;e<8;e++)
      fiin[(size_t)b*512 + e*64 + k] = fmaxf(acc[e] + bp[k*8+e], 0.f);
  }
}

// ---- FI linear (+relu+residual): res[b][o] over grid (oc=8, b=16) ----
__global__ __launch_bounds__(256) void k_fi(const float* __restrict__ fiin,
    const float* __restrict__ Wf, const float* __restrict__ bfi, float* __restrict__ res){
  int oc = blockIdx.x, b = blockIdx.y;
  int tid = threadIdx.x;
  int og = tid & 63, q = tid >> 6;
  int o = oc*64 + og;
  __shared__ float row[512];
  __shared__ float part[4][64];
  reinterpret_cast<float2*>(row)[tid] = reinterpret_cast<const float2*>(fiin + (size_t)b*512)[tid];
  __syncthreads();
  float acc = 0.f;
  const float* wp = Wf + (size_t)(q*128)*512 + o;
  const float* rp = &row[q*128];
#pragma unroll 4
  for (int d=0; d<128; ++d) acc += rp[d] * wp[(size_t)d*512];
  part[q][og] = acc;
  __syncthreads();
  if (q==0){
    float s = part[0][og]+part[1][og]+part[2][og]+part[3][og];
    res[(size_t)b*512 + o] = fmaxf(s + bfi[o], 0.f) + row[o];
  }
}

// ---- Set linear (+relu): vec[b][o2] over grid (oc=2, b=16) ----
__global__ __launch_bounds__(256) void k_set(const float* __restrict__ res,
    const float* __restrict__ Ws, const float* __restrict__ bs, float* __restrict__ vecst_l){
  int oc = blockIdx.x, b = blockIdx.y;
  int tid = threadIdx.x;
  int og = tid & 63, q = tid >> 6;
  int o = oc*64 + og;
  __shared__ float row[512];
  __shared__ float part[4][64];
  reinterpret_cast<float2*>(row)[tid] = reinterpret_cast<const float2*>(res + (size_t)b*512)[tid];
  __syncthreads();
  float acc = 0.f;
  const float* wp = Ws + (size_t)(q*128)*128 + o;
  const float* rp = &row[q*128];
#pragma unroll 4
  for (int d=0; d<128; ++d) acc += rp[d] * wp[(size_t)d*128];
  part[q][og] = acc;
  __syncthreads();
  if (q==0){
    vecst_l[(size_t)b*128 + o] = fmaxf(part[0][og]+part[1][og]+part[2][og]+part[3][og] + bs[o], 0.f);
  }
}

// ---- head-sum (inline normalize), att_dis, t_emb update with LN ----
__global__ __launch_bounds__(256) void k_update(float* __restrict__ temb, const float* __restrict__ att2,
    const float* __restrict__ smax, const float* __restrict__ sinv,
    const float* __restrict__ wp1, const float* __restrict__ bp1,
    const float* __restrict__ gn, const float* __restrict__ ben,
    float* __restrict__ attdis, int layer){
  int bl = blockIdx.x;            // 0..B*L-1
  int tid = threadIdx.x;
  __shared__ float sred[9];
  int wave = tid>>6, lane = tid&63;
  if (tid < 64){
    int b = bl >> 10;
    float raw = att2[(size_t)bl*64 + tid];
    float a = __expf(raw - smax[b*64+tid]) * sinv[b*64+tid];
    float t = waveSum(a);
    if (tid==0){
      sred[8] = t;
      int lseq = bl & 1023;
      attdis[(size_t)(layer*B_ + b)*L_ + lseq] = t;
    }
  }
  __syncthreads();
  float sa = sred[8];
  int d0 = tid*2;
  float2 e = *reinterpret_cast<const float2*>(&temb[(size_t)bl*512 + d0]);
  float2 uw  = *reinterpret_cast<const float2*>(wp1 + d0);
  float2 ubp = *reinterpret_cast<const float2*>(bp1 + d0);
  float v0 = e.x * (sa*uw.x + ubp.x + 1.0f);
  float v1 = e.y * (sa*uw.y + ubp.y + 1.0f);
  float s1 = v0+v1, s2 = v0*v0+v1*v1;
  float w1 = waveSum(s1), w2 = waveSum(s2);
  if (lane==0){ sred[wave]=w1; sred[4+wave]=w2; }
  __syncthreads();
  s1 = sred[0]+sred[1]+sred[2]+sred[3];
  s2 = sred[4]+sred[5]+sred[6]+sred[7];
  float m = s1*(1.f/512.f);
  float var = s2*(1.f/512.f) - m*m;
  float rstd = rsqrtf(var+1e-5f);
  float2 ug  = *reinterpret_cast<const float2*>(gn + d0);
  float2 ube = *reinterpret_cast<const float2*>(ben + d0);
  float2 o;
  o.x = (v0-m)*rstd*ug.x + ube.x;
  o.y = (v1-m)*rstd*ug.y + ube.y;
  *reinterpret_cast<float2*>(&temb[(size_t)bl*512 + d0]) = o;
}

// ---- final attention rate ----
__global__ __launch_bounds__(64) void k_aat_rate(const float* __restrict__ temb,
    const float* __restrict__ w_aat, const float* __restrict__ b_aat, float* __restrict__ ratef){
  int bl = blockIdx.x; int lane = threadIdx.x;
  const float* rp = temb + (size_t)bl*512 + lane*8;
  float4 e0 = *reinterpret_cast<const float4*>(rp);
  float4 e1 = *reinterpret_cast<const float4*>(rp+4);
  const float* wp = w_aat + lane*8;
  float4 w0 = *reinterpret_cast<const float4*>(wp);
  float4 w1 = *reinterpret_cast<const float4*>(wp+4);
  float s = e0.x*w0.x+e0.y*w0.y+e0.z*w0.z+e0.w*w0.w
          + e1.x*w1.x+e1.y*w1.y+e1.z*w1.z+e1.w*w1.w;
  s = waveSum(s);
  if (lane==0) ratef[bl] = fmaxf(s + b_aat[0], 0.f);
}

// ---- softmax over a contiguous 1024-run per block ----
__global__ __launch_bounds__(256) void k_softmax_seq(float* __restrict__ ratef){
  int b = blockIdx.x; int tid = threadIdx.x;
  float* base = ratef + (size_t)b*1024;
  float4 v = reinterpret_cast<float4*>(base)[tid];
  float mx = fmaxf(fmaxf(v.x,v.y),fmaxf(v.z,v.w));
  __shared__ float red[8];
  int wave=tid>>6, lane=tid&63;
  float wm = waveMax(mx);
  if(lane==0) red[wave]=wm;
  __syncthreads();
  mx = fmaxf(fmaxf(red[0],red[1]),fmaxf(red[2],red[3]));
  v.x=__expf(v.x-mx); v.y=__expf(v.y-mx); v.z=__expf(v.z-mx); v.w=__expf(v.w-mx);
  float s = v.x+v.y+v.z+v.w;
  float wsum = waveSum(s);
  if(lane==0) red[4+wave]=wsum;
  __syncthreads();
  s = red[4]+red[5]+red[6]+red[7];
  float inv = 1.f/s;
  v.x*=inv;v.y*=inv;v.z*=inv;v.w*=inv;
  reinterpret_cast<float4*>(base)[tid] = v;
}

// ---- final pool partials ----
__global__ __launch_bounds__(256) void k_poolA(const float* __restrict__ temb, const float* __restrict__ attf,
                                               float* __restrict__ sraw){
  int dc = blockIdx.x, b = blockIdx.y;
  int tid = threadIdx.x;
  int dl = tid & 63, q = tid >> 6;
  int d = dc*64 + dl;
  __shared__ float sA[1024];
  __shared__ float part[4][64];
  reinterpret_cast<float4*>(sA)[tid] = reinterpret_cast<const float4*>(attf + (size_t)b*1024)[tid];
  __syncthreads();
  float acc = 0.f;
  const float* tp = temb + ((size_t)b*1024 + q*256)*512 + d;
  const float* ap = &sA[q*256];
#pragma unroll 4
  for (int l=0;l<256;++l) acc += tp[(size_t)l*512]*ap[l];
  part[q][dl] = acc;
  __syncthreads();
  if (q==0) sraw[(size_t)b*512 + d] = (part[0][dl]+part[1][dl]+part[2][dl]+part[3][dl])*0.03125f;
}

// ---- final pool LN ----
__global__ __launch_bounds__(256) void k_poolB(const float* __restrict__ sraw,
   const float* __restrict__ g_aat, const float* __restrict__ be_aat, float* __restrict__ spool){
  int b = blockIdx.x; int tid = threadIdx.x;
  int d0 = tid*2;
  float2 a = *reinterpret_cast<const float2*>(&sraw[(size_t)b*512 + d0]);
  __shared__ float red[8];
  int wave=tid>>6,lane=tid&63;
  float s1 = a.x+a.y, s2 = a.x*a.x+a.y*a.y;
  float w1=waveSum(s1), w2=waveSum(s2);
  if(lane==0){red[wave]=w1; red[4+wave]=w2;}
  __syncthreads();
  s1=red[0]+red[1]+red[2]+red[3];
  s2=red[4]+red[5]+red[6]+red[7];
  float m=s1*(1.f/512.f), var=s2*(1.f/512.f)-m*m, rstd=rsqrtf(var+1e-5f);
  float2 ug=*reinterpret_cast<const float2*>(g_aat+d0);
  float2 ub=*reinterpret_cast<const float2*>(be_aat+d0);
  spool[(size_t)b*512+d0]   = (a.x-m)*rstd*ug.x+ub.x;
  spool[(size_t)b*512+d0+1] = (a.y-m)*rstd*ug.y+ub.y;
}

// ---- final head ----
__global__ __launch_bounds__(256) void k_final(const float* __restrict__ spool, const float* __restrict__ vecst,
    const float* __restrict__ Wh, const float* __restrict__ bh, float* __restrict__ Pout){
  int b = blockIdx.x; int tid = threadIdx.x;
  float part = 0.f;
  for (int i = tid; i < 2560; i += 256){
    float v;
    if (i < 512) v = spool[(size_t)b*512 + i];
    else {
      int j = i - 512;
      v = vecst[(size_t)(j>>7)*(B_*SET_) + b*SET_ + (j&127)];
    }
    part += v * Wh[i];
  }
  __shared__ float red[4];
  int wave=tid>>6,lane=tid&63;
  float w = waveSum(part);
  if(lane==0) red[wave]=w;
  __syncthreads();
  if (tid==0){
    float x = red[0]+red[1]+red[2]+red[3] + bh[0];
    Pout[b] = 1.0f/(1.0f+expf(-x));
  }
}

extern "C" void kernel_launch(void* const* d_in, const int* in_sizes, int n_in,
                              void* d_out, int out_size, void* d_ws, size_t ws_size,
                              hipStream_t stream){
  const float* emb   = (const float*)d_in[0];
  const float* W_att = (const float*)d_in[1];
  const float* b_att = (const float*)d_in[2];
  const float* g_att = (const float*)d_in[3];
  const float* be_att= (const float*)d_in[4];
  const float* W_pro = (const float*)d_in[5];
  const float* b_pro = (const float*)d_in[6];
  const float* w_p1  = (const float*)d_in[7];
  const float* b_p1  = (const float*)d_in[8];
  const float* W_FI  = (const float*)d_in[9];
  const float* b_FI  = (const float*)d_in[10];
  const float* W_Set = (const float*)d_in[11];
  const float* b_Set = (const float*)d_in[12];
  const float* g_n   = (const float*)d_in[13];
  const float* be_n  = (const float*)d_in[14];
  const float* w_aat = (const float*)d_in[15];
  const float* b_aat = (const float*)d_in[16];
  const float* g_aat = (const float*)d_in[17];
  const float* be_aat= (const float*)d_in[18];
  const float* W_h2p = (const float*)d_in[19];
  const float* b_h2p = (const float*)d_in[20];
  float* out = (float*)d_out;

  float* ws = (float*)d_ws;
  float* temb  = ws;                      // 8,388,608
  float* att2  = temb + 8388608;          // 1,048,576  [B][L][K] raw relu scores
  float* spart = att2 + 1048576;          // 2,097,152
  float* fiin  = spart + 2097152;         // 8,192
  float* vecst = fiin + 8192;             // 131,072
  float* ratef = vecst + 131072;          // 16,384
  float* spool = ratef + 16384;           // 8,192
  float* res   = spool + 8192;            // 8,192
  float* sraw  = res + 8192;              // 8,192
  float* Wat   = sraw + 8192;             // 524,288  [NL][D][K]
  float* maxs4 = Wat + 524288;            // 4,096
  float* sums4 = maxs4 + 4096;            // 4,096
  float* smax  = sums4 + 4096;            // 1,024
  float* sinv  = smax + 1024;             // 1,024

  hipMemcpyAsync(temb, emb, (size_t)8388608*4, hipMemcpyDeviceToDevice, stream);
  k_wt<<<16,256,0,stream>>>(W_att, Wat);
  for (int l=0; l<16; ++l){
    k_rate_gemm<<<512,256,0,stream>>>(temb, Wat + (size_t)l*32768, b_att + l*64, att2);
    k_stat64<<<dim3(4,16),256,0,stream>>>(att2, maxs4, sums4);
    k_statc<<<16,64,0,stream>>>(maxs4, sums4, smax, sinv);
    k_spart_gemm<<<dim3(8,4,16),256,0,stream>>>(temb, att2, smax, sinv, spart);
    k_sln_vec<<<1024,64,0,stream>>>(spart, g_att + (size_t)l*32768, be_att + (size_t)l*32768,
                                    W_pro + (size_t)l*262144, b_pro + l*512, fiin);
    k_fi<<<dim3(8,16),256,0,stream>>>(fiin, W_FI + (size_t)l*262144, b_FI + l*512, res);
    k_set<<<dim3(2,16),256,0,stream>>>(res, W_Set + (size_t)l*65536, b_Set + l*128,
                                       vecst + (size_t)l*2048);
    k_update<<<16384,256,0,stream>>>(temb, att2, smax, sinv, w_p1 + l*512, b_p1 + l*512,
                                     g_n + l*512, be_n + l*512, out + 16, l);
  }
  k_aat_rate<<<16384,64,0,stream>>>(temb, w_aat, b_aat, ratef);
  k_softmax_seq<<<16,256,0,stream>>>(ratef);
  k_poolA<<<dim3(8,16),256,0,stream>>>(temb, ratef, sraw);
  k_poolB<<<16,256,0,stream>>>(sraw, g_aat, be_aat, spool);
  k_final<<<16,256,0,stream>>>(spool, vecst, W_h2p, b_h2p, out);
}